// Round 2
// baseline (277.302 us; speedup 1.0000x reference)
//
#include <hip/hip_runtime.h>
#include <hip/hip_bf16.h>

// Problem constants
#define S_      1024
#define B_      2
#define H_      1024
#define E_      8
#define FFN_    1408
#define TWO_FFN 2816
#define T_      2048          // B_*S_
#define MAXSLOTS 5120
// prep kernel block partition (4 tiles per transpose block, pipelined)
#define NB_T1   1408            // w1: 5632 tiles / 4
#define NB_T2   704             // w2: 2816 tiles / 4
#define NB_CONV 512             // convert+gate
#define NB_PREP (NB_T1 + NB_T2 + NB_CONV)

typedef float  f32x4 __attribute__((ext_vector_type(4)));
typedef short  s16x8 __attribute__((ext_vector_type(8)));

// ---------- helpers ----------
__device__ __forceinline__ unsigned short f2bf(float f) {
    unsigned u = __float_as_uint(f);
    u += 0x7fffu + ((u >> 16) & 1u);          // round-to-nearest-even
    return (unsigned short)(u >> 16);
}
__device__ __forceinline__ void async16(const void* g, void* l) {
    __builtin_amdgcn_global_load_lds(
        (const __attribute__((address_space(1))) unsigned int*)(unsigned long long)g,
        (__attribute__((address_space(3))) unsigned int*)(unsigned long long)l,
        16, 0, 0);
}
__device__ __forceinline__ size_t xrow_off(int t) {
    return (size_t)(t & (S_ - 1)) * (B_ * H_) + (size_t)(t >> 10) * H_;
}

// ---------- 1. merged prep: w1 transpose | w2 transpose | convert+gate ----------
// Pipelined 64x64 transpose, 4 tiles/block, 2 LDS buffers, 1 barrier/tile.
// lds pad 65: write bank = (4q+j+rr)&31 -> 2-way (free); read 2-way (free).
__device__ __forceinline__ void t_load(const float* __restrict__ s, int C, float4 v[4]) {
#pragma unroll
    for (int i = 0; i < 4; i++)
        v[i] = *(const float4*)(s + (size_t)i * 16 * C);
}
__device__ __forceinline__ void t_write(float (*lds)[65], int q, int rr, const float4 v[4]) {
#pragma unroll
    for (int i = 0; i < 4; i++) {
        int r = rr + 16 * i;
        lds[q * 4 + 0][r] = v[i].x;
        lds[q * 4 + 1][r] = v[i].y;
        lds[q * 4 + 2][r] = v[i].z;
        lds[q * 4 + 3][r] = v[i].w;
    }
}
__device__ __forceinline__ void t_drain(const float (*lds)[65], unsigned short* __restrict__ d,
                                        int R, int oq, int cc) {
#pragma unroll
    for (int i = 0; i < 2; i++) {
        const float* row = &lds[cc + 32 * i][oq * 8];
        unsigned short o[8];
#pragma unroll
        for (int j = 0; j < 8; j++) o[j] = f2bf(row[j]);
        *(uint4*)(d + (size_t)(32 * i) * R) = *(const uint4*)o;
    }
}

__global__ void k_prep(const float* __restrict__ hs, const float* __restrict__ gw,
                       const float* __restrict__ w1, const float* __restrict__ w2,
                       unsigned short* __restrict__ xb,
                       unsigned short* __restrict__ w1bt, unsigned short* __restrict__ w2bt,
                       int* __restrict__ topkI, float* __restrict__ topkW) {
    __shared__ float tile[2][64][65];
    int bx = blockIdx.x, tid = threadIdx.x;
    if (bx < NB_T1 + NB_T2) {
        int R, C, tt0, perE;
        const float* ip; unsigned short* op;
        bool isW1 = (bx < NB_T1);
        if (isW1) { R = H_;   C = TWO_FFN; ip = w1; op = w1bt; tt0 = bx * 4;            perE = 44 * 16; }
        else      { R = FFN_; C = H_;      ip = w2; op = w2bt; tt0 = (bx - NB_T1) * 4;  perE = 16 * 22; }
        int q  = tid & 15, rr = tid >> 4;    // load mapping
        int oq = tid & 7,  cc = tid >> 3;    // drain mapping
        const float* s[4]; unsigned short* d[4];
#pragma unroll
        for (int j = 0; j < 4; j++) {
            int tt = tt0 + j;
            int e = tt / perE, rem = tt - e * perE;
            int r0, c0;
            if (isW1) { r0 = (rem & 15) << 6;  c0 = (rem >> 4) << 6; }
            else      { r0 = (rem % 22) << 6;  c0 = (rem / 22) << 6; }
            s[j] = ip + (size_t)e * R * C + (size_t)(r0 + rr) * C + c0 + q * 4;
            d[j] = op + (size_t)e * R * C + (size_t)(c0 + cc) * R + r0 + oq * 8;
        }
        float4 v0[4], v1[4];
        t_load(s[0], C, v0);
        t_load(s[1], C, v1);
        t_write(tile[0], q, rr, v0);
        __syncthreads();
        t_load(s[2], C, v0);                 // tile 2 in flight
        t_write(tile[1], q, rr, v1);         // tile 1 -> buf1
        t_drain(tile[0], d[0], R, oq, cc);   // tile 0 out
        __syncthreads();
        t_load(s[3], C, v1);                 // tile 3 in flight
        t_write(tile[0], q, rr, v0);         // tile 2 -> buf0
        t_drain(tile[1], d[1], R, oq, cc);   // tile 1 out
        __syncthreads();
        t_write(tile[1], q, rr, v1);         // tile 3 -> buf1
        t_drain(tile[0], d[2], R, oq, cc);   // tile 2 out
        __syncthreads();
        t_drain(tile[1], d[3], R, oq, cc);   // tile 3 out
        return;
    }
    // convert + gate (no global atomics)
    int cb = bx - (NB_T1 + NB_T2);
    int wid = tid >> 6, lane = tid & 63;
    int t = cb * 4 + wid;
    const float* xr = hs + xrow_off(t);
    unsigned short* xo = xb + (size_t)t * H_;
    float acc[E_];
#pragma unroll
    for (int e = 0; e < E_; e++) acc[e] = 0.f;
#pragma unroll
    for (int p = 0; p < 4; p++) {
        int h = p * 256 + lane * 4;
        const float4 v = *(const float4*)(xr + h);
        unsigned short o[4] = { f2bf(v.x), f2bf(v.y), f2bf(v.z), f2bf(v.w) };
        *(uint2*)(xo + h) = *(const uint2*)o;
#pragma unroll
        for (int e = 0; e < E_; e++) {
            const float4 g = *(const float4*)(gw + e * H_ + h);
            acc[e] += v.x * g.x + v.y * g.y + v.z * g.z + v.w * g.w;
        }
    }
#pragma unroll
    for (int e = 0; e < E_; e++)
        for (int off = 32; off > 0; off >>= 1) acc[e] += __shfl_down(acc[e], off);
    if (lane == 0) {
        float l0 = -1e30f, l1 = -1e30f; int i0 = 0, i1 = 0;
#pragma unroll
        for (int e = 0; e < E_; e++) {
            float v = acc[e];
            if (v > l0)      { l1 = l0; i1 = i0; l0 = v; i0 = e; }
            else if (v > l1) { l1 = v;  i1 = e; }
        }
        float p1 = expf(l1 - l0);                 // p0 = 1
        float w0 = 1.f / (1.f + p1);
        float w1s = 1.f - w0;
        topkI[2 * t] = i0; topkI[2 * t + 1] = i1;
        topkW[2 * t] = w0; topkW[2 * t + 1] = w1s;
    }
}

// ---------- 2. fused histogram + route + assign (one block) ----------
// ctrl ints: [40+e]=ntile(e)  [48+e]=slotBase(e)
__global__ void k_routeassign(const int* __restrict__ topkI, const float* __restrict__ topkW,
                              int* __restrict__ ctrl, int* __restrict__ perm,
                              int* __restrict__ slotOfTok) {
    __shared__ int s_wcnt[4][E_];
    __shared__ int s_base[E_];
    __shared__ int s_cur[E_];
    int tid = threadIdx.x, wid = tid >> 6, lane = tid & 63;
    int cnt[E_];
#pragma unroll
    for (int j = 0; j < E_; j++) cnt[j] = 0;
    for (int i = tid; i < 2 * T_; i += 256) {
        int e = topkI[i];
#pragma unroll
        for (int j = 0; j < E_; j++) cnt[j] += (e == j);
    }
#pragma unroll
    for (int j = 0; j < E_; j++)
        for (int off = 32; off > 0; off >>= 1) cnt[j] += __shfl_down(cnt[j], off);
    if (lane == 0) {
#pragma unroll
        for (int j = 0; j < E_; j++) s_wcnt[wid][j] = cnt[j];
    }
    __syncthreads();
    if (tid == 0) {
        int b = 0;
        for (int e = 0; e < E_; e++) {
            int n = s_wcnt[0][e] + s_wcnt[1][e] + s_wcnt[2][e] + s_wcnt[3][e];
            int ntile = (n + 127) >> 7;
            s_base[e] = b;
            ctrl[40 + e] = ntile;
            ctrl[48 + e] = b;
            b += ntile * 128;
        }
#pragma unroll
        for (int e = 0; e < E_; e++) s_cur[e] = 0;
    }
    __syncthreads();
    for (int s = tid; s < MAXSLOTS; s += 256) perm[s] = 0;   // padded slots -> token 0 (safe)
    __syncthreads();
    for (int t = tid; t < T_; t += 256) {
#pragma unroll
        for (int k = 0; k < 2; k++) {
            int e = topkI[2 * t + k];
            int pos = atomicAdd(&s_cur[e], 1);   // LDS atomic
            int slot = s_base[e] + pos;
            perm[slot] = t;
            slotOfTok[2 * t + k] = slot;
        }
    }
}

// ---------- 3. GEMM1 + fused swiglu epilogue ----------
// Grid: x = e + 8*ct (176), y = tile-in-expert (16): same (e,ct) => same XCD => B-slice L2 reuse.
__global__ __launch_bounds__(256) void k_gemm1(
    const unsigned short* __restrict__ xb, const unsigned short* __restrict__ w1bt,
    const int* __restrict__ ctrl, const int* __restrict__ perm,
    unsigned short* __restrict__ A2) {
    int e  = blockIdx.x & 7;
    int ct = blockIdx.x >> 3;                   // 0..21
    int ti = blockIdx.y;
    if (ti >= ctrl[40 + e]) return;
    int slot0 = ctrl[48 + e] + ti * 128;
    __shared__ __align__(16) unsigned short smem[2 * 128 * 64];   // As | Bs, reused as fp32 upLds
    unsigned short* As = smem;
    unsigned short* Bs = smem + 128 * 64;
    int tid = threadIdx.x, wid = tid >> 6, lane = tid & 63;

    const unsigned short* aPtr[4];
    const unsigned short* bPtr[4];
    unsigned short* lA[4];
    unsigned short* lB[4];
#pragma unroll
    for (int i = 0; i < 4; i++) {
        int c = (wid * 4 + i) * 64 + lane;      // chunk id 0..1023
        int r = c >> 3;
        int qd = (c & 7) ^ (r & 7);             // XOR swizzle
        int col8 = qd * 8;
        int tok = perm[slot0 + r];
        int gr = (r < 64) ? (ct * 64 + r) : (FFN_ + ct * 64 + (r - 64));  // gate/up rows
        aPtr[i] = xb + (size_t)tok * H_ + col8;
        bPtr[i] = w1bt + ((size_t)e * TWO_FFN + gr) * H_ + col8;
        lA[i] = As + (size_t)c * 8;
        lB[i] = Bs + (size_t)c * 8;
    }
    f32x4 acc[4][4];
#pragma unroll
    for (int mi = 0; mi < 4; mi++)
#pragma unroll
        for (int ni = 0; ni < 4; ni++) acc[mi][ni] = (f32x4){0.f, 0.f, 0.f, 0.f};
    int wm = wid & 1, wn = wid >> 1;
    int rowB = wm * 64, colB = wn * 64;
    int sw = (lane & 7) << 3;

    for (int k0 = 0; k0 < H_; k0 += 64) {
#pragma unroll
        for (int i = 0; i < 4; i++) { async16(aPtr[i] + k0, lA[i]); async16(bPtr[i] + k0, lB[i]); }
        __syncthreads();
#pragma unroll
        for (int kk = 0; kk < 64; kk += 32) {
            int kr = (kk + ((lane >> 4) << 3)) ^ sw;
            s16x8 af[4], bf[4];
#pragma unroll
            for (int mi = 0; mi < 4; mi++) af[mi] = *(const s16x8*)&As[(rowB + mi * 16 + (lane & 15)) * 64 + kr];
#pragma unroll
            for (int ni = 0; ni < 4; ni++) bf[ni] = *(const s16x8*)&Bs[(colB + ni * 16 + (lane & 15)) * 64 + kr];
#pragma unroll
            for (int mi = 0; mi < 4; mi++)
#pragma unroll
                for (int ni = 0; ni < 4; ni++)
                    acc[mi][ni] = __builtin_amdgcn_mfma_f32_16x16x32_bf16(af[mi], bf[ni], acc[mi][ni], 0, 0, 0);
        }
        __syncthreads();
    }
    // ---- fused swiglu epilogue ----
    float* upLds = (float*)smem;                // 128 x 64 fp32 = 32 KB
    if (wn == 1) {
#pragma unroll
        for (int mi = 0; mi < 4; mi++)
#pragma unroll
            for (int ni = 0; ni < 4; ni++)
#pragma unroll
                for (int r = 0; r < 4; r++) {
                    int m = rowB + mi * 16 + (lane >> 4) * 4 + r;
                    int u = ni * 16 + (lane & 15);
                    upLds[m * 64 + u] = acc[mi][ni][r];
                }
    }
    __syncthreads();
    if (wn == 0) {
#pragma unroll
        for (int mi = 0; mi < 4; mi++)
#pragma unroll
            for (int r = 0; r < 4; r++) {
                int m = rowB + mi * 16 + (lane >> 4) * 4 + r;
                unsigned short* arow = A2 + (size_t)(slot0 + m) * FFN_ + ct * 64;
#pragma unroll
                for (int ni = 0; ni < 4; ni++) {
                    int gl = ni * 16 + (lane & 15);
                    float g = acc[mi][ni][r];
                    float u = upLds[m * 64 + gl];
                    float s = g / (1.f + expf(-g));
                    arow[gl] = f2bf(s * u);
                }
            }
    }
}

// ---------- 4. GEMM2 (split-K=2): A2[128,1408] @ w2bt^T -> Yp bf16 partials ----------
__global__ __launch_bounds__(256) void k_gemm2(
    const unsigned short* __restrict__ A2, const unsigned short* __restrict__ w2bt,
    const int* __restrict__ ctrl, unsigned short* __restrict__ Yp) {
    int e  = blockIdx.x & 7;
    int ct = blockIdx.x >> 3;                   // 0..7
    int ti = blockIdx.y;
    if (ti >= ctrl[40 + e]) return;
    int slot0 = ctrl[48 + e] + ti * 128;
    int ks    = blockIdx.z;
    __shared__ __align__(16) unsigned short As[128 * 64];
    __shared__ __align__(16) unsigned short Bs[128 * 64];
    int tid = threadIdx.x, wid = tid >> 6, lane = tid & 63;

    const unsigned short* aPtr[4];
    const unsigned short* bPtr[4];
    unsigned short* lA[4];
    unsigned short* lB[4];
#pragma unroll
    for (int i = 0; i < 4; i++) {
        int c = (wid * 4 + i) * 64 + lane;
        int r = c >> 3;
        int qd = (c & 7) ^ (r & 7);
        int col8 = qd * 8;
        aPtr[i] = A2 + (size_t)(slot0 + r) * FFN_ + col8;
        bPtr[i] = w2bt + ((size_t)e * H_ + ct * 128 + r) * FFN_ + col8;
        lA[i] = As + (size_t)c * 8;
        lB[i] = Bs + (size_t)c * 8;
    }
    f32x4 acc[4][4];
#pragma unroll
    for (int mi = 0; mi < 4; mi++)
#pragma unroll
        for (int ni = 0; ni < 4; ni++) acc[mi][ni] = (f32x4){0.f, 0.f, 0.f, 0.f};
    int wm = wid & 1, wn = wid >> 1;
    int rowB = wm * 64, colB = wn * 64;
    int sw = (lane & 7) << 3;

    int kbeg = ks * (FFN_ / 2), kend = kbeg + FFN_ / 2;   // 11 steps each
    for (int k0 = kbeg; k0 < kend; k0 += 64) {
#pragma unroll
        for (int i = 0; i < 4; i++) { async16(aPtr[i] + k0, lA[i]); async16(bPtr[i] + k0, lB[i]); }
        __syncthreads();
#pragma unroll
        for (int kk = 0; kk < 64; kk += 32) {
            int kr = (kk + ((lane >> 4) << 3)) ^ sw;
            s16x8 af[4], bf[4];
#pragma unroll
            for (int mi = 0; mi < 4; mi++) af[mi] = *(const s16x8*)&As[(rowB + mi * 16 + (lane & 15)) * 64 + kr];
#pragma unroll
            for (int ni = 0; ni < 4; ni++) bf[ni] = *(const s16x8*)&Bs[(colB + ni * 16 + (lane & 15)) * 64 + kr];
#pragma unroll
            for (int mi = 0; mi < 4; mi++)
#pragma unroll
                for (int ni = 0; ni < 4; ni++)
                    acc[mi][ni] = __builtin_amdgcn_mfma_f32_16x16x32_bf16(af[mi], bf[ni], acc[mi][ni], 0, 0, 0);
        }
        __syncthreads();
    }
    unsigned short* yp = Yp + (size_t)ks * MAXSLOTS * H_;
#pragma unroll
    for (int mi = 0; mi < 4; mi++)
#pragma unroll
        for (int r = 0; r < 4; r++) {
            int m = rowB + mi * 16 + (lane >> 4) * 4 + r;
#pragma unroll
            for (int ni = 0; ni < 4; ni++) {
                int n = colB + ni * 16 + (lane & 15);
                yp[(size_t)(slot0 + m) * H_ + ct * 128 + n] = f2bf(acc[mi][ni][r]);
            }
        }
}

// ---------- 5. combine (bf16 partials) ----------
__global__ void k_combine(const unsigned short* __restrict__ Yp, const int* __restrict__ slotOfTok,
                          const float* __restrict__ topkW, float* __restrict__ out) {
    int t = blockIdx.x;
    int h = threadIdx.x * 4;
    int sA = slotOfTok[2 * t], sB = slotOfTok[2 * t + 1];
    float wA = topkW[2 * t],   wB = topkW[2 * t + 1];
    const unsigned short* pA0 = Yp + (size_t)sA * H_ + h;
    const unsigned short* pA1 = Yp + ((size_t)MAXSLOTS + sA) * H_ + h;
    const unsigned short* pB0 = Yp + (size_t)sB * H_ + h;
    const unsigned short* pB1 = Yp + ((size_t)MAXSLOTS + sB) * H_ + h;
    unsigned short a0[4], a1[4], b0[4], b1[4];
    *(uint2*)a0 = *(const uint2*)pA0;
    *(uint2*)a1 = *(const uint2*)pA1;
    *(uint2*)b0 = *(const uint2*)pB0;
    *(uint2*)b1 = *(const uint2*)pB1;
    float4 r;
    float* rp = (float*)&r;
#pragma unroll
    for (int i = 0; i < 4; i++) {
        float av = __uint_as_float(((unsigned)a0[i]) << 16) + __uint_as_float(((unsigned)a1[i]) << 16);
        float bv = __uint_as_float(((unsigned)b0[i]) << 16) + __uint_as_float(((unsigned)b1[i]) << 16);
        rp[i] = wA * av + wB * bv;
    }
    *(float4*)(out + xrow_off(t) + h) = r;
}

extern "C" void kernel_launch(void* const* d_in, const int* in_sizes, int n_in,
                              void* d_out, int out_size, void* d_ws, size_t ws_size,
                              hipStream_t stream) {
    (void)in_sizes; (void)n_in; (void)ws_size; (void)out_size;
    const float* hs = (const float*)d_in[0];
    const float* gw = (const float*)d_in[1];
    const float* w1 = (const float*)d_in[2];
    const float* w2 = (const float*)d_in[3];
    float* out = (float*)d_out;
    char* ws = (char*)d_ws;

    int*            ctrl   = (int*)ws;                                  // 1 KB
    int*            topkI  = (int*)(ws + (16u << 10));                  // 16 KB
    float*          topkW  = (float*)(ws + (48u << 10));                // 16 KB
    int*            perm   = (int*)(ws + (80u << 10));                  // 20 KB
    int*            slotOfTok = (int*)(ws + (144u << 10));              // 16 KB
    unsigned short* xb    = (unsigned short*)(ws + (1ull  << 20));      // 4 MiB
    unsigned short* w1bt  = (unsigned short*)(ws + (5ull  << 20));      // 44 MiB (dead after gemm1)
    unsigned short* Yp    = (unsigned short*)(ws + (5ull << 20));       // 20 MiB — ALIASES w1bt
    unsigned short* w2bt  = (unsigned short*)(ws + (49ull << 20));      // 22 MiB
    unsigned short* A2    = (unsigned short*)(ws + (71ull << 20));      // 13.75 MiB -> end ~85 MiB

    k_prep<<<NB_PREP, 256, 0, stream>>>(hs, gw, w1, w2, xb, w1bt, w2bt, topkI, topkW);
    k_routeassign<<<1, 256, 0, stream>>>(topkI, topkW, ctrl, perm, slotOfTok);
    k_gemm1<<<dim3(8 * (FFN_ / 64), 16), 256, 0, stream>>>(xb, w1bt, ctrl, perm, A2);
    k_gemm2<<<dim3(8 * (H_ / 128), 16, 2), 256, 0, stream>>>(A2, w2bt, ctrl, Yp);
    k_combine<<<2048, 256, 0, stream>>>(Yp, slotOfTok, topkW, out);
}